// Round 19
// baseline (37.843 us; speedup 1.0000x reference)
//
#include <hip/hip_runtime.h>

constexpr int B = 8, N = 1024, FIN = 128, FOUT = 64, H = 4;
constexpr float LOG2E = 1.44269504f;

typedef __attribute__((ext_vector_type(8))) short short8;
typedef __attribute__((ext_vector_type(4))) short short4v;
typedef __attribute__((ext_vector_type(4))) float f32x4;

// f32 -> bf16 round-to-nearest-even (prep-kernel use only)
static __device__ inline unsigned short f2bf(float x) {
    union { float f; unsigned u; } v; v.f = x;
    unsigned r = v.u + 0x7fff + ((v.u >> 16) & 1);
    return (unsigned short)(r >> 16);
}

// ---------------------------------------------------------------------------
// Fused prep kernel — R18-verified VERBATIM.
// Blocks 0..511: mbB. Blocks 512..767: h_prime MFMA GEMM + ei/ej.
// ---------------------------------------------------------------------------
__global__ __launch_bounds__(256) void gat_prep(
    const float* __restrict__ h,      // (B,N,FIN)
    const float* __restrict__ W,      // (H,FIN,FOUT)
    const float* __restrict__ a,      // (H,2*FOUT,1)
    const int*   __restrict__ adj,    // (N,N)
    const float* __restrict__ bias,   // (N,N)
    unsigned short* __restrict__ hpF, // fragment-order bf16 (4 MB)
    unsigned short* __restrict__ mbB, // fragment-order bf16 (2 MB)
    float* __restrict__ ei_t,         // (B,H,N) *LOG2E
    float* __restrict__ ej_t)         // (B,H,N) *LOG2E
{
    __shared__ float h_lds[32][132];
    const int t = threadIdx.x;

    if (blockIdx.x < 512) {           // ---- mb part (R11-verified) ----
        const int bx   = blockIdx.x;
        const int ti   = bx >> 3;
        const int jc   = (bx & 7) * 4 + (t >> 6);
        const int lane = t & 63;
        const int i    = ti * 16 + (lane & 15);
        const int j0   = jc * 32 + 8 * (lane >> 4);

        const int4*   ap = reinterpret_cast<const int4*>(adj + (size_t)i * N + j0);
        const float4* bp = reinterpret_cast<const float4*>(bias + (size_t)i * N + j0);
        int4   a0 = ap[0], a1 = ap[1];
        float4 b0 = bp[0], b1 = bp[1];
        unsigned short q0 = f2bf(a0.x ? LOG2E * b0.x : -1e35f);
        unsigned short q1 = f2bf(a0.y ? LOG2E * b0.y : -1e35f);
        unsigned short q2 = f2bf(a0.z ? LOG2E * b0.z : -1e35f);
        unsigned short q3 = f2bf(a0.w ? LOG2E * b0.w : -1e35f);
        unsigned short q4 = f2bf(a1.x ? LOG2E * b1.x : -1e35f);
        unsigned short q5 = f2bf(a1.y ? LOG2E * b1.y : -1e35f);
        unsigned short q6 = f2bf(a1.z ? LOG2E * b1.z : -1e35f);
        unsigned short q7 = f2bf(a1.w ? LOG2E * b1.w : -1e35f);
        int4 ov;
        ov.x = (int)((unsigned)q0 | ((unsigned)q1 << 16));
        ov.y = (int)((unsigned)q2 | ((unsigned)q3 << 16));
        ov.z = (int)((unsigned)q4 | ((unsigned)q5 << 16));
        ov.w = (int)((unsigned)q6 | ((unsigned)q7 << 16));
        *reinterpret_cast<int4*>(mbB + (((size_t)ti * 32 + jc) * 64 + lane) * 8) = ov;
        return;
    }

    // ---- h_prime part: MFMA, 32 rows per block, wave = head ----
    const int blk = blockIdx.x - 512;        // 0..255
    const int b   = blk >> 5;                // / (N/32)
    const int n0  = (blk & 31) * 32;

    {   // stage 32 rows x 128 f32 (16.9KB): 1024 float4, 4 per thread
        const float* src = h + ((size_t)b * N + n0) * FIN;
        for (int v = t; v < 1024; v += 256) {
            float4 x = reinterpret_cast<const float4*>(src)[v];
            int fl = v * 4;
            *reinterpret_cast<float4*>(&h_lds[fl >> 7][fl & 127]) = x;
        }
    }

    const int hd   = t >> 6;
    const int lane = t & 63;
    const int li   = lane & 15;
    const int kg   = lane >> 4;

    // Build W B-fragments: wf[ks][ft][e] = bf16(W[hd][ks*32+8kg+e][16ft+li])
    short8 wf[4][4];
    {
        const float* Wp = W + (size_t)hd * FIN * FOUT;
        #pragma unroll
        for (int ks = 0; ks < 4; ++ks)
            #pragma unroll
            for (int ft = 0; ft < 4; ++ft) {
                const float* wb = Wp + (size_t)(ks * 32 + 8 * kg) * FOUT + 16 * ft + li;
                int4 pk_;
                float u0 = wb[0],       u1 = wb[64],      u2 = wb[128], u3 = wb[192];
                float u4 = wb[256],     u5 = wb[320],     u6 = wb[384], u7 = wb[448];
                asm("v_cvt_pk_bf16_f32 %0, %1, %2" : "=v"(pk_.x) : "v"(u0), "v"(u1));
                asm("v_cvt_pk_bf16_f32 %0, %1, %2" : "=v"(pk_.y) : "v"(u2), "v"(u3));
                asm("v_cvt_pk_bf16_f32 %0, %1, %2" : "=v"(pk_.z) : "v"(u4), "v"(u5));
                asm("v_cvt_pk_bf16_f32 %0, %1, %2" : "=v"(pk_.w) : "v"(u6), "v"(u7));
                wf[ks][ft] = *reinterpret_cast<short8*>(&pk_);
            }
    }
    __syncthreads();                          // h_lds ready

    f32x4 c[4][2];                            // [ft][rt]
    #pragma unroll
    for (int ft = 0; ft < 4; ++ft)
        #pragma unroll
        for (int rt = 0; rt < 2; ++rt) c[ft][rt] = f32x4{0.f, 0.f, 0.f, 0.f};

    #pragma unroll
    for (int rt = 0; rt < 2; ++rt) {
        #pragma unroll
        for (int ks = 0; ks < 4; ++ks) {
            const float* hp8 = &h_lds[16 * rt + li][ks * 32 + 8 * kg];
            float4 x0 = *reinterpret_cast<const float4*>(hp8);
            float4 x1 = *reinterpret_cast<const float4*>(hp8 + 4);
            int4 pk_;
            asm("v_cvt_pk_bf16_f32 %0, %1, %2" : "=v"(pk_.x) : "v"(x0.x), "v"(x0.y));
            asm("v_cvt_pk_bf16_f32 %0, %1, %2" : "=v"(pk_.y) : "v"(x0.z), "v"(x0.w));
            asm("v_cvt_pk_bf16_f32 %0, %1, %2" : "=v"(pk_.z) : "v"(x1.x), "v"(x1.y));
            asm("v_cvt_pk_bf16_f32 %0, %1, %2" : "=v"(pk_.w) : "v"(x1.z), "v"(x1.w));
            short8 af = *reinterpret_cast<short8*>(&pk_);
            c[0][rt] = __builtin_amdgcn_mfma_f32_16x16x32_bf16(af, wf[ks][0], c[0][rt], 0, 0, 0);
            c[1][rt] = __builtin_amdgcn_mfma_f32_16x16x32_bf16(af, wf[ks][1], c[1][rt], 0, 0, 0);
            c[2][rt] = __builtin_amdgcn_mfma_f32_16x16x32_bf16(af, wf[ks][2], c[2][rt], 0, 0, 0);
            c[3][rt] = __builtin_amdgcn_mfma_f32_16x16x32_bf16(af, wf[ks][3], c[3][rt], 0, 0, 0);
        }
    }

    const int bh = b * H + hd;
    const int jc = n0 >> 5;
    #pragma unroll
    for (int ft = 0; ft < 4; ++ft)
        #pragma unroll
        for (int rt = 0; rt < 2; ++rt) {
            short4v v4;
            v4[0] = (short)f2bf(c[ft][rt][0]);
            v4[1] = (short)f2bf(c[ft][rt][1]);
            v4[2] = (short)f2bf(c[ft][rt][2]);
            v4[3] = (short)f2bf(c[ft][rt][3]);
            const int lanep = li + 16 * (2 * rt + (kg >> 1));
            *reinterpret_cast<short4v*>(
                hpF + ((((size_t)bh * 32 + jc) * 4 + ft) * 64 + lanep) * 8 + 4 * (kg & 1)) = v4;
        }

    float a1v[4], a2v[4];
    #pragma unroll
    for (int ft = 0; ft < 4; ++ft) {
        a1v[ft] = a[(size_t)hd * 2 * FOUT + 16 * ft + li];
        a2v[ft] = a[(size_t)hd * 2 * FOUT + FOUT + 16 * ft + li];
    }
    #pragma unroll
    for (int rt = 0; rt < 2; ++rt)
        #pragma unroll
        for (int r = 0; r < 4; ++r) {
            float e1 = c[0][rt][r] * a1v[0] + c[1][rt][r] * a1v[1]
                     + c[2][rt][r] * a1v[2] + c[3][rt][r] * a1v[3];
            float e2 = c[0][rt][r] * a2v[0] + c[1][rt][r] * a2v[1]
                     + c[2][rt][r] * a2v[2] + c[3][rt][r] * a2v[3];
            #pragma unroll
            for (int m = 1; m < 16; m <<= 1) {
                e1 += __shfl_xor(e1, m, 64);
                e2 += __shfl_xor(e2, m, 64);
            }
            if (li == 0) {
                int rr = n0 + 16 * rt + 4 * kg + r;
                ei_t[(size_t)bh * N + rr] = LOG2E * e1;
                ej_t[(size_t)bh * N + rr] = LOG2E * e2;
            }
        }
}

// ---------------------------------------------------------------------------
// Kernel B: fused scores+softmax+PV. R17/R18 structure + T5 s_setprio(1)
// around the 5-MFMA cluster (single change this round). Mechanism: the
// merged-phase counted-vmcnt schedule gives waves role diversity per phase
// (score-VALU vs MFMA vs load-issue); priority keeps the MFMA pipe fed
// (catalog m218b: +21-39% on exactly this structure class).
// ---------------------------------------------------------------------------
__global__ __launch_bounds__(512) void gat_attn(
    const unsigned short* __restrict__ hpF, // fragment-order bf16
    const float* __restrict__ ei_t,         // (B,H,N) *LOG2E
    const float* __restrict__ ej_t,         // (B,H,N) *LOG2E
    const unsigned short* __restrict__ mbB, // fragment-order bf16 masked bias
    float* __restrict__ out)                // (B,N,H*FOUT)
{
    __shared__ __align__(16) char smem[32768];   // hstage[4] x 8KB; red (20KB) aliased after loop
    typedef unsigned short hstage_t[2][4][512];
    hstage_t* hstage = reinterpret_cast<hstage_t*>(smem);

    const int raw  = blockIdx.x;            // 512
    const int xcd  = raw & 7;
    const int k_   = raw >> 3;
    const int bh   = ((xcd >> 1) << 3) | (k_ >> 3);          // 8 bh per XCD
    const int it0  = (((xcd & 1) << 3) | (k_ & 7)) * 4;      // 4 i-tiles/block
    const int t    = threadIdx.x;
    const int w8   = t >> 6;
    const int w    = w8 & 3;                // i-tile (also f-tile staged)
    const int jh   = w8 >> 2;               // j-half
    const int lane = t & 63;
    const int li   = lane & 15;
    const int kg   = lane >> 4;
    const int ti   = it0 + w;
    const int irow = ti * 16 + li;
    const int jcb  = jh * 16;               // first chunk of this wave's half

    const float  ei0   = ei_t[(size_t)bh * N + irow];
    const float* ejrow = ej_t + (size_t)bh * N;
    const unsigned short* mrow = mbB + ((size_t)ti * 32 * 64 + lane) * 8;  // + jc*512
    const size_t hbase = (size_t)bh * 65536;                               // u16/slab

    f32x4 c0 = {0.f,0.f,0.f,0.f}, c1 = {0.f,0.f,0.f,0.f};
    f32x4 c2 = {0.f,0.f,0.f,0.f}, c3 = {0.f,0.f,0.f,0.f};
    f32x4 c4 = {0.f,0.f,0.f,0.f};
    const short obf = (short)0x3F80;                      // bf16 1.0
    const short8 ones = {obf,obf,obf,obf,obf,obf,obf,obf};

    #define VMCNT6() asm volatile("s_waitcnt vmcnt(6)" ::: "memory")
    #define BARRIER() { __builtin_amdgcn_s_barrier(); asm volatile("" ::: "memory"); }

    // stage f-tile w of chunk JCG into hstage[BUF][jh][w]
    #define STAGE(BUF, JCG) {                                                 \
        const unsigned short* gs_ = hpF + hbase + (size_t)(JCG) * 2048        \
                                        + (size_t)w * 512 + (size_t)lane * 8; \
        __builtin_amdgcn_global_load_lds(                                     \
            (const __attribute__((address_space(1))) void*)gs_,               \
            (__attribute__((address_space(3))) void*)&hstage[BUF][jh][w][0],  \
            16, 0, 0); }

    // register prefetch for chunk JCG into set S (mq + 2 ej float4s)
    #define REGS(S, JCG) {                                                    \
        mq##S  = *reinterpret_cast<const int4*>(mrow + (size_t)(JCG) * 512);  \
        ejA##S = *reinterpret_cast<const float4*>(ejrow + (JCG) * 32 + 8 * kg);\
        ejB##S = *reinterpret_cast<const float4*>(ejrow + (JCG) * 32 + 8 * kg + 4); }

    #define DSREAD(BUF, BA, BB, BC, BD) {                                     \
        BA = *reinterpret_cast<const short8*>(&hstage[BUF][jh][0][lane * 8]); \
        BB = *reinterpret_cast<const short8*>(&hstage[BUF][jh][1][lane * 8]); \
        BC = *reinterpret_cast<const short8*>(&hstage[BUF][jh][2][lane * 8]); \
        BD = *reinterpret_cast<const short8*>(&hstage[BUF][jh][3][lane * 8]); }

    // two scores from one packed-bf16 word (lo = even elem, hi = odd elem)
    #define SCORE2(PL, PH, EJL, EJH, QW) {                                    \
        float bl_ = __uint_as_float(((unsigned)(QW)) << 16);                  \
        float bh_ = __uint_as_float(((unsigned)(QW)) & 0xffff0000u);          \
        float el_ = ei0 + (EJL); el_ = fmaxf(el_, 0.2f * el_) + bl_;          \
        float eh_ = ei0 + (EJH); eh_ = fmaxf(eh_, 0.2f * eh_) + bh_;          \
        asm("v_exp_f32 %0, %1" : "=v"(PL) : "v"(el_));                        \
        asm("v_exp_f32 %0, %1" : "=v"(PH) : "v"(eh_)); }

    #define COMPS(S, BA, BB, BC, BD) {                                        \
        float p0,p1,p2,p3,p4,p5,p6,p7;                                        \
        SCORE2(p0, p1, ejA##S.x, ejA##S.y, mq##S.x)                           \
        SCORE2(p2, p3, ejA##S.z, ejA##S.w, mq##S.y)                           \
        SCORE2(p4, p5, ejB##S.x, ejB##S.y, mq##S.z)                           \
        SCORE2(p6, p7, ejB##S.z, ejB##S.w, mq##S.w)                           \
        int4 pk_;                                                             \
        asm("v_cvt_pk_bf16_f32 %0, %1, %2" : "=v"(pk_.x) : "v"(p0), "v"(p1)); \
        asm("v_cvt_pk_bf16_f32 %0, %1, %2" : "=v"(pk_.y) : "v"(p2), "v"(p3)); \
        asm("v_cvt_pk_bf16_f32 %0, %1, %2" : "=v"(pk_.z) : "v"(p4), "v"(p5)); \
        asm("v_cvt_pk_bf16_f32 %0, %1, %2" : "=v"(pk_.w) : "v"(p6), "v"(p7)); \
        short8 a0_ = *reinterpret_cast<short8*>(&pk_);                        \
        __builtin_amdgcn_s_setprio(1);                                        \
        c0 = __builtin_amdgcn_mfma_f32_16x16x32_bf16(a0_, BA, c0, 0, 0, 0);   \
        c1 = __builtin_amdgcn_mfma_f32_16x16x32_bf16(a0_, BB, c1, 0, 0, 0);   \
        c2 = __builtin_amdgcn_mfma_f32_16x16x32_bf16(a0_, BC, c2, 0, 0, 0);   \
        c3 = __builtin_amdgcn_mfma_f32_16x16x32_bf16(a0_, BD, c3, 0, 0, 0);   \
        c4 = __builtin_amdgcn_mfma_f32_16x16x32_bf16(a0_, ones, c4, 0, 0, 0); \
        __builtin_amdgcn_s_setprio(0); }

    short8 A0, B0, C0, D0, A1, B1, C1, D1;
    int4 mq0, mq1;
    float4 ejA0, ejB0, ejA1, ejB1;

    // prologue: stage chunks 0,1 (buf 0,1); regs for chunks 0,1.
    STAGE(0, jcb + 0)
    STAGE(1, jcb + 1)
    REGS(0, jcb + 0)
    REGS(1, jcb + 1)
    VMCNT6();                                // both STAGEs retired
    BARRIER();

    // 8 merged phases; phase k consumes chunks k,k+1 from bufs k%4,(k+1)%4
    // and stages chunks k+2,k+3 into bufs (k+2)%4,(k+3)%4.
    #pragma unroll 1
    for (int k = 0; k < 16; k += 2) {
        const int pa = (k + 2 < 16) ? jcb + k + 2 : jcb + 15;   // clamped prefetch
        const int pb = (k + 3 < 16) ? jcb + k + 3 : jcb + 15;
        const int ba = k & 2 ? 2 : 0;        // k%4 (k even)
        const int bb = ba + 1;               // (k+1)%4
        const int bn0 = ba ^ 2;              // (k+2)%4
        const int bn1 = bb ^ 2;              // (k+3)%4
        // issue next-phase stages up front
        STAGE(bn0, pa)
        STAGE(bn1, pb)
        // consume chunk k
        DSREAD(ba, A0, B0, C0, D0)
        COMPS(0, A0, B0, C0, D0)
        REGS(0, pa)
        // consume chunk k+1
        DSREAD(bb, A1, B1, C1, D1)
        COMPS(1, A1, B1, C1, D1)
        REGS(1, pb)
        VMCNT6();                            // retires this phase's 2 STAGEs (oldest)
        BARRIER();
    }
    #undef VMCNT6
    #undef BARRIER
    #undef STAGE
    #undef REGS
    #undef DSREAD
    #undef SCORE2
    #undef COMPS

    // hstage is dead from here on: alias the reduce buffer over it
    f32x4 (*red)[4][64] = reinterpret_cast<f32x4 (*)[4][64]>(smem);

    __syncthreads();                         // everyone past final DSREAD
    if (jh == 1) {
        red[0][w][lane] = c0;
        red[1][w][lane] = c1;
        red[2][w][lane] = c2;
        red[3][w][lane] = c3;
        red[4][w][lane] = c4;
    }
    __syncthreads();
    if (jh == 1) return;

    c0 += red[0][w][lane];
    c1 += red[1][w][lane];
    c2 += red[2][w][lane];
    c3 += red[3][w][lane];
    c4 += red[4][w][lane];

    // C layout col=li (f within tile), row=4*kg+r; c4[r] = that row's sum.
    const int b  = bh >> 2;
    const int hd = bh & 3;
    #pragma unroll
    for (int r = 0; r < 4; ++r) {
        int orow = ti * 16 + 4 * kg + r;
        float inv = 1.0f / c4[r];
        float* ob = out + (((size_t)b * N + orow) * H + hd) * 64 + li;
        ob[0]  = c0[r] * inv;
        ob[16] = c1[r] * inv;
        ob[32] = c2[r] * inv;
        ob[48] = c3[r] * inv;
    }
}

extern "C" void kernel_launch(void* const* d_in, const int* in_sizes, int n_in,
                              void* d_out, int out_size, void* d_ws, size_t ws_size,
                              hipStream_t stream) {
    const float* h    = (const float*)d_in[0];
    const int*   adj  = (const int*)  d_in[1];
    const float* bias = (const float*)d_in[2];
    const float* W    = (const float*)d_in[3];
    const float* a    = (const float*)d_in[4];
    float* out = (float*)d_out;

    char* ws = (char*)d_ws;
    unsigned short* hpF = (unsigned short*)ws;                        // 4 MB
    unsigned short* mbB = (unsigned short*)(ws + ((size_t)4 << 20));  // 2 MB
    float* ei_t = (float*)(ws + ((size_t)6 << 20));                   // 128 KB
    float* ej_t = ei_t + (size_t)B * H * N;                           // 128 KB

    gat_prep<<<512 + B * N / 32, 256, 0, stream>>>(h, W, a, adj, bias,
                                                   hpF, mbB, ei_t, ej_t);
    gat_attn<<<B * H * (N / 64), 512, 0, stream>>>(hpF, ei_t, ej_t, mbB, out);
}

// Round 20
// 34.400 us; speedup vs baseline: 1.1001x; 1.1001x over previous
//
#include <hip/hip_runtime.h>

constexpr int B = 8, N = 1024, FIN = 128, FOUT = 64, H = 4;
constexpr float LOG2E = 1.44269504f;

typedef __attribute__((ext_vector_type(8))) short short8;
typedef __attribute__((ext_vector_type(4))) short short4v;
typedef __attribute__((ext_vector_type(4))) float f32x4;

// f32 -> bf16 round-to-nearest-even (prep-kernel use only)
static __device__ inline unsigned short f2bf(float x) {
    union { float f; unsigned u; } v; v.f = x;
    unsigned r = v.u + 0x7fff + ((v.u >> 16) & 1);
    return (unsigned short)(r >> 16);
}

// ---------------------------------------------------------------------------
// Fused prep kernel. Blocks 0..511: mbB via LDS TRANSPOSE (new this round):
//   phase 1: coalesced adj/bias reads (thread=(row r, granule g), 512B runs),
//            masked-bf16 pack, store to 4KB LDS tile (XOR-16B swizzle per row);
//   phase 2: gather fragment from LDS (~2-way conflicts), COALESCED mbB write.
//   (R18's version had 16-way 4KB-strided global reads — the pre-R8 attn
//   pathology.)
// Blocks 512..767: h_prime MFMA GEMM + ei/ej — R18-verified VERBATIM.
// ---------------------------------------------------------------------------
__global__ __launch_bounds__(256) void gat_prep(
    const float* __restrict__ h,      // (B,N,FIN)
    const float* __restrict__ W,      // (H,FIN,FOUT)
    const float* __restrict__ a,      // (H,2*FOUT,1)
    const int*   __restrict__ adj,    // (N,N)
    const float* __restrict__ bias,   // (N,N)
    unsigned short* __restrict__ hpF, // fragment-order bf16 (4 MB)
    unsigned short* __restrict__ mbB, // fragment-order bf16 (2 MB)
    float* __restrict__ ei_t,         // (B,H,N) *LOG2E
    float* __restrict__ ej_t)         // (B,H,N) *LOG2E
{
    __shared__ float h_lds[32][132];
    const int t = threadIdx.x;

    if (blockIdx.x < 512) {           // ---- mb part: coalesced + LDS transpose ----
        unsigned short* mlds = reinterpret_cast<unsigned short*>(h_lds); // 4KB reuse
        const int bx = blockIdx.x;
        const int ti = bx >> 3;            // 16-row i-tile
        const int j0 = (bx & 7) * 128;     // 128-j slab

        // phase 1: thread = (row r, granule g of 8 j's); reads are 512B runs/row
        const int r = t >> 4;
        const int g = t & 15;
        const size_t src = (size_t)(ti * 16 + r) * N + j0 + g * 8;
        const int4*   ap = reinterpret_cast<const int4*>(adj + src);
        const float4* bp = reinterpret_cast<const float4*>(bias + src);
        int4   a0 = ap[0], a1 = ap[1];
        float4 b0 = bp[0], b1 = bp[1];
        unsigned short q0 = f2bf(a0.x ? LOG2E * b0.x : -1e35f);
        unsigned short q1 = f2bf(a0.y ? LOG2E * b0.y : -1e35f);
        unsigned short q2 = f2bf(a0.z ? LOG2E * b0.z : -1e35f);
        unsigned short q3 = f2bf(a0.w ? LOG2E * b0.w : -1e35f);
        unsigned short q4 = f2bf(a1.x ? LOG2E * b1.x : -1e35f);
        unsigned short q5 = f2bf(a1.y ? LOG2E * b1.y : -1e35f);
        unsigned short q6 = f2bf(a1.z ? LOG2E * b1.z : -1e35f);
        unsigned short q7 = f2bf(a1.w ? LOG2E * b1.w : -1e35f);
        int4 ov;
        ov.x = (int)((unsigned)q0 | ((unsigned)q1 << 16));
        ov.y = (int)((unsigned)q2 | ((unsigned)q3 << 16));
        ov.z = (int)((unsigned)q4 | ((unsigned)q5 << 16));
        ov.w = (int)((unsigned)q6 | ((unsigned)q7 << 16));
        // LDS store: logical mlds[r][g*8+e], XOR-swizzled 16B granule per row
        *reinterpret_cast<int4*>(&mlds[r * 128 + ((g ^ (r & 7)) * 8)]) = ov;
        __syncthreads();

        // phase 2: wave w = jc_local; lane gathers its fragment, writes coalesced
        const int w    = t >> 6;
        const int lane = t & 63;
        const int li   = lane & 15;
        const int kg   = lane >> 4;
        const int gr   = w * 4 + kg;       // source granule
        int4 ov2 = *reinterpret_cast<const int4*>(
            &mlds[li * 128 + ((gr ^ (li & 7)) * 8)]);
        const int jc = (bx & 7) * 4 + w;
        *reinterpret_cast<int4*>(mbB + (((size_t)ti * 32 + jc) * 64 + lane) * 8) = ov2;
        return;
    }

    // ---- h_prime part: MFMA, 32 rows per block, wave = head (R18 verbatim) ----
    const int blk = blockIdx.x - 512;        // 0..255
    const int b   = blk >> 5;                // / (N/32)
    const int n0  = (blk & 31) * 32;

    {   // stage 32 rows x 128 f32 (16.9KB): 1024 float4, 4 per thread
        const float* src = h + ((size_t)b * N + n0) * FIN;
        for (int v = t; v < 1024; v += 256) {
            float4 x = reinterpret_cast<const float4*>(src)[v];
            int fl = v * 4;
            *reinterpret_cast<float4*>(&h_lds[fl >> 7][fl & 127]) = x;
        }
    }

    const int hd   = t >> 6;
    const int lane = t & 63;
    const int li   = lane & 15;
    const int kg   = lane >> 4;

    // Build W B-fragments: wf[ks][ft][e] = bf16(W[hd][ks*32+8kg+e][16ft+li])
    short8 wf[4][4];
    {
        const float* Wp = W + (size_t)hd * FIN * FOUT;
        #pragma unroll
        for (int ks = 0; ks < 4; ++ks)
            #pragma unroll
            for (int ft = 0; ft < 4; ++ft) {
                const float* wb = Wp + (size_t)(ks * 32 + 8 * kg) * FOUT + 16 * ft + li;
                int4 pk_;
                float u0 = wb[0],       u1 = wb[64],      u2 = wb[128], u3 = wb[192];
                float u4 = wb[256],     u5 = wb[320],     u6 = wb[384], u7 = wb[448];
                asm("v_cvt_pk_bf16_f32 %0, %1, %2" : "=v"(pk_.x) : "v"(u0), "v"(u1));
                asm("v_cvt_pk_bf16_f32 %0, %1, %2" : "=v"(pk_.y) : "v"(u2), "v"(u3));
                asm("v_cvt_pk_bf16_f32 %0, %1, %2" : "=v"(pk_.z) : "v"(u4), "v"(u5));
                asm("v_cvt_pk_bf16_f32 %0, %1, %2" : "=v"(pk_.w) : "v"(u6), "v"(u7));
                wf[ks][ft] = *reinterpret_cast<short8*>(&pk_);
            }
    }
    __syncthreads();                          // h_lds ready

    f32x4 c[4][2];                            // [ft][rt]
    #pragma unroll
    for (int ft = 0; ft < 4; ++ft)
        #pragma unroll
        for (int rt = 0; rt < 2; ++rt) c[ft][rt] = f32x4{0.f, 0.f, 0.f, 0.f};

    #pragma unroll
    for (int rt = 0; rt < 2; ++rt) {
        #pragma unroll
        for (int ks = 0; ks < 4; ++ks) {
            const float* hp8 = &h_lds[16 * rt + li][ks * 32 + 8 * kg];
            float4 x0 = *reinterpret_cast<const float4*>(hp8);
            float4 x1 = *reinterpret_cast<const float4*>(hp8 + 4);
            int4 pk_;
            asm("v_cvt_pk_bf16_f32 %0, %1, %2" : "=v"(pk_.x) : "v"(x0.x), "v"(x0.y));
            asm("v_cvt_pk_bf16_f32 %0, %1, %2" : "=v"(pk_.y) : "v"(x0.z), "v"(x0.w));
            asm("v_cvt_pk_bf16_f32 %0, %1, %2" : "=v"(pk_.z) : "v"(x1.x), "v"(x1.y));
            asm("v_cvt_pk_bf16_f32 %0, %1, %2" : "=v"(pk_.w) : "v"(x1.z), "v"(x1.w));
            short8 af = *reinterpret_cast<short8*>(&pk_);
            c[0][rt] = __builtin_amdgcn_mfma_f32_16x16x32_bf16(af, wf[ks][0], c[0][rt], 0, 0, 0);
            c[1][rt] = __builtin_amdgcn_mfma_f32_16x16x32_bf16(af, wf[ks][1], c[1][rt], 0, 0, 0);
            c[2][rt] = __builtin_amdgcn_mfma_f32_16x16x32_bf16(af, wf[ks][2], c[2][rt], 0, 0, 0);
            c[3][rt] = __builtin_amdgcn_mfma_f32_16x16x32_bf16(af, wf[ks][3], c[3][rt], 0, 0, 0);
        }
    }

    const int bh = b * H + hd;
    const int jc = n0 >> 5;
    #pragma unroll
    for (int ft = 0; ft < 4; ++ft)
        #pragma unroll
        for (int rt = 0; rt < 2; ++rt) {
            short4v v4;
            v4[0] = (short)f2bf(c[ft][rt][0]);
            v4[1] = (short)f2bf(c[ft][rt][1]);
            v4[2] = (short)f2bf(c[ft][rt][2]);
            v4[3] = (short)f2bf(c[ft][rt][3]);
            const int lanep = li + 16 * (2 * rt + (kg >> 1));
            *reinterpret_cast<short4v*>(
                hpF + ((((size_t)bh * 32 + jc) * 4 + ft) * 64 + lanep) * 8 + 4 * (kg & 1)) = v4;
        }

    float a1v[4], a2v[4];
    #pragma unroll
    for (int ft = 0; ft < 4; ++ft) {
        a1v[ft] = a[(size_t)hd * 2 * FOUT + 16 * ft + li];
        a2v[ft] = a[(size_t)hd * 2 * FOUT + FOUT + 16 * ft + li];
    }
    #pragma unroll
    for (int rt = 0; rt < 2; ++rt)
        #pragma unroll
        for (int r = 0; r < 4; ++r) {
            float e1 = c[0][rt][r] * a1v[0] + c[1][rt][r] * a1v[1]
                     + c[2][rt][r] * a1v[2] + c[3][rt][r] * a1v[3];
            float e2 = c[0][rt][r] * a2v[0] + c[1][rt][r] * a2v[1]
                     + c[2][rt][r] * a2v[2] + c[3][rt][r] * a2v[3];
            #pragma unroll
            for (int m = 1; m < 16; m <<= 1) {
                e1 += __shfl_xor(e1, m, 64);
                e2 += __shfl_xor(e2, m, 64);
            }
            if (li == 0) {
                int rr = n0 + 16 * rt + 4 * kg + r;
                ei_t[(size_t)bh * N + rr] = LOG2E * e1;
                ej_t[(size_t)bh * N + rr] = LOG2E * e2;
            }
        }
}

// ---------------------------------------------------------------------------
// Kernel B: fused scores+softmax+PV — R18-verified VERBATIM (34.7µs; R19's
// setprio reverted: −3.1µs regression, uniform-role waves get no arbitration
// benefit and the priority delays next-phase STAGE issue).
// ---------------------------------------------------------------------------
__global__ __launch_bounds__(512) void gat_attn(
    const unsigned short* __restrict__ hpF, // fragment-order bf16
    const float* __restrict__ ei_t,         // (B,H,N) *LOG2E
    const float* __restrict__ ej_t,         // (B,H,N) *LOG2E
    const unsigned short* __restrict__ mbB, // fragment-order bf16 masked bias
    float* __restrict__ out)                // (B,N,H*FOUT)
{
    __shared__ __align__(16) char smem[32768];   // hstage[4] x 8KB; red (20KB) aliased after loop
    typedef unsigned short hstage_t[2][4][512];
    hstage_t* hstage = reinterpret_cast<hstage_t*>(smem);

    const int raw  = blockIdx.x;            // 512
    const int xcd  = raw & 7;
    const int k_   = raw >> 3;
    const int bh   = ((xcd >> 1) << 3) | (k_ >> 3);          // 8 bh per XCD
    const int it0  = (((xcd & 1) << 3) | (k_ & 7)) * 4;      // 4 i-tiles/block
    const int t    = threadIdx.x;
    const int w8   = t >> 6;
    const int w    = w8 & 3;                // i-tile (also f-tile staged)
    const int jh   = w8 >> 2;               // j-half
    const int lane = t & 63;
    const int li   = lane & 15;
    const int kg   = lane >> 4;
    const int ti   = it0 + w;
    const int irow = ti * 16 + li;
    const int jcb  = jh * 16;               // first chunk of this wave's half

    const float  ei0   = ei_t[(size_t)bh * N + irow];
    const float* ejrow = ej_t + (size_t)bh * N;
    const unsigned short* mrow = mbB + ((size_t)ti * 32 * 64 + lane) * 8;  // + jc*512
    const size_t hbase = (size_t)bh * 65536;                               // u16/slab

    f32x4 c0 = {0.f,0.f,0.f,0.f}, c1 = {0.f,0.f,0.f,0.f};
    f32x4 c2 = {0.f,0.f,0.f,0.f}, c3 = {0.f,0.f,0.f,0.f};
    f32x4 c4 = {0.f,0.f,0.f,0.f};
    const short obf = (short)0x3F80;                      // bf16 1.0
    const short8 ones = {obf,obf,obf,obf,obf,obf,obf,obf};

    #define VMCNT6() asm volatile("s_waitcnt vmcnt(6)" ::: "memory")
    #define BARRIER() { __builtin_amdgcn_s_barrier(); asm volatile("" ::: "memory"); }

    // stage f-tile w of chunk JCG into hstage[BUF][jh][w]
    #define STAGE(BUF, JCG) {                                                 \
        const unsigned short* gs_ = hpF + hbase + (size_t)(JCG) * 2048        \
                                        + (size_t)w * 512 + (size_t)lane * 8; \
        __builtin_amdgcn_global_load_lds(                                     \
            (const __attribute__((address_space(1))) void*)gs_,               \
            (__attribute__((address_space(3))) void*)&hstage[BUF][jh][w][0],  \
            16, 0, 0); }

    // register prefetch for chunk JCG into set S (mq + 2 ej float4s)
    #define REGS(S, JCG) {                                                    \
        mq##S  = *reinterpret_cast<const int4*>(mrow + (size_t)(JCG) * 512);  \
        ejA##S = *reinterpret_cast<const float4*>(ejrow + (JCG) * 32 + 8 * kg);\
        ejB##S = *reinterpret_cast<const float4*>(ejrow + (JCG) * 32 + 8 * kg + 4); }

    #define DSREAD(BUF, BA, BB, BC, BD) {                                     \
        BA = *reinterpret_cast<const short8*>(&hstage[BUF][jh][0][lane * 8]); \
        BB = *reinterpret_cast<const short8*>(&hstage[BUF][jh][1][lane * 8]); \
        BC = *reinterpret_cast<const short8*>(&hstage[BUF][jh][2][lane * 8]); \
        BD = *reinterpret_cast<const short8*>(&hstage[BUF][jh][3][lane * 8]); }

    // two scores from one packed-bf16 word (lo = even elem, hi = odd elem)
    #define SCORE2(PL, PH, EJL, EJH, QW) {                                    \
        float bl_ = __uint_as_float(((unsigned)(QW)) << 16);                  \
        float bh_ = __uint_as_float(((unsigned)(QW)) & 0xffff0000u);          \
        float el_ = ei0 + (EJL); el_ = fmaxf(el_, 0.2f * el_) + bl_;          \
        float eh_ = ei0 + (EJH); eh_ = fmaxf(eh_, 0.2f * eh_) + bh_;          \
        asm("v_exp_f32 %0, %1" : "=v"(PL) : "v"(el_));                        \
        asm("v_exp_f32 %0, %1" : "=v"(PH) : "v"(eh_)); }

    #define COMPS(S, BA, BB, BC, BD) {                                        \
        float p0,p1,p2,p3,p4,p5,p6,p7;                                        \
        SCORE2(p0, p1, ejA##S.x, ejA##S.y, mq##S.x)                           \
        SCORE2(p2, p3, ejA##S.z, ejA##S.w, mq##S.y)                           \
        SCORE2(p4, p5, ejB##S.x, ejB##S.y, mq##S.z)                           \
        SCORE2(p6, p7, ejB##S.z, ejB##S.w, mq##S.w)                           \
        int4 pk_;                                                             \
        asm("v_cvt_pk_bf16_f32 %0, %1, %2" : "=v"(pk_.x) : "v"(p0), "v"(p1)); \
        asm("v_cvt_pk_bf16_f32 %0, %1, %2" : "=v"(pk_.y) : "v"(p2), "v"(p3)); \
        asm("v_cvt_pk_bf16_f32 %0, %1, %2" : "=v"(pk_.z) : "v"(p4), "v"(p5)); \
        asm("v_cvt_pk_bf16_f32 %0, %1, %2" : "=v"(pk_.w) : "v"(p6), "v"(p7)); \
        short8 a0_ = *reinterpret_cast<short8*>(&pk_);                        \
        c0 = __builtin_amdgcn_mfma_f32_16x16x32_bf16(a0_, BA, c0, 0, 0, 0);   \
        c1 = __builtin_amdgcn_mfma_f32_16x16x32_bf16(a0_, BB, c1, 0, 0, 0);   \
        c2 = __builtin_amdgcn_mfma_f32_16x16x32_bf16(a0_, BC, c2, 0, 0, 0);   \
        c3 = __builtin_amdgcn_mfma_f32_16x16x32_bf16(a0_, BD, c3, 0, 0, 0);   \
        c4 = __builtin_amdgcn_mfma_f32_16x16x32_bf16(a0_, ones, c4, 0, 0, 0); }

    short8 A0, B0, C0, D0, A1, B1, C1, D1;
    int4 mq0, mq1;
    float4 ejA0, ejB0, ejA1, ejB1;

    // prologue: stage chunks 0,1 (buf 0,1); regs for chunks 0,1.
    STAGE(0, jcb + 0)
    STAGE(1, jcb + 1)
    REGS(0, jcb + 0)
    REGS(1, jcb + 1)
    VMCNT6();                                // both STAGEs retired
    BARRIER();

    // 8 merged phases; phase k consumes chunks k,k+1 from bufs k%4,(k+1)%4
    // and stages chunks k+2,k+3 into bufs (k+2)%4,(k+3)%4.
    #pragma unroll 1
    for (int k = 0; k < 16; k += 2) {
        const int pa = (k + 2 < 16) ? jcb + k + 2 : jcb + 15;   // clamped prefetch
        const int pb = (k + 3 < 16) ? jcb + k + 3 : jcb + 15;
        const int ba = k & 2 ? 2 : 0;        // k%4 (k even)
        const int bb = ba + 1;               // (k+1)%4
        const int bn0 = ba ^ 2;              // (k+2)%4
        const int bn1 = bb ^ 2;              // (k+3)%4
        // issue next-phase stages up front
        STAGE(bn0, pa)
        STAGE(bn1, pb)
        // consume chunk k
        DSREAD(ba, A0, B0, C0, D0)
        COMPS(0, A0, B0, C0, D0)
        REGS(0, pa)
        // consume chunk k+1
        DSREAD(bb, A1, B1, C1, D1)
        COMPS(1, A1, B1, C1, D1)
        REGS(1, pb)
        VMCNT6();                            // retires this phase's 2 STAGEs (oldest)
        BARRIER();
    }
    #undef VMCNT6
    #undef BARRIER
    #undef STAGE
    #undef REGS
    #undef DSREAD
    #undef SCORE2
    #undef COMPS

    // hstage is dead from here on: alias the reduce buffer over it
    f32x4 (*red)[4][64] = reinterpret_cast<f32x4 (*)[4][64]>(smem);

    __syncthreads();                         // everyone past final DSREAD
    if (jh == 1) {
        red[0][w][lane] = c0;
        red[1][w][lane] = c1;
        red[2][w][lane] = c2;
        red[3][w][lane] = c3;
        red[4][w][lane] = c4;
    }
    __syncthreads();
    if (jh == 1) return;

    c0 += red[0][w][lane];
    c1 += red[1][w][lane];
    c2 += red[2][w][lane];
    c3 += red[3][w][lane];
    c4 += red[4][w][lane];

    // C layout col=li (f within tile), row=4*kg+r; c4[r] = that row's sum.
    const int b  = bh >> 2;
    const int hd = bh & 3;
    #pragma unroll
    for (int r = 0; r < 4; ++r) {
        int orow = ti * 16 + 4 * kg + r;
        float inv = 1.0f / c4[r];
        float* ob = out + (((size_t)b * N + orow) * H + hd) * 64 + li;
        ob[0]  = c0[r] * inv;
        ob[16] = c1[r] * inv;
        ob[32] = c2[r] * inv;
        ob[48] = c3[r] * inv;
    }
}

extern "C" void kernel_launch(void* const* d_in, const int* in_sizes, int n_in,
                              void* d_out, int out_size, void* d_ws, size_t ws_size,
                              hipStream_t stream) {
    const float* h    = (const float*)d_in[0];
    const int*   adj  = (const int*)  d_in[1];
    const float* bias = (const float*)d_in[2];
    const float* W    = (const float*)d_in[3];
    const float* a    = (const float*)d_in[4];
    float* out = (float*)d_out;

    char* ws = (char*)d_ws;
    unsigned short* hpF = (unsigned short*)ws;                        // 4 MB
    unsigned short* mbB = (unsigned short*)(ws + ((size_t)4 << 20));  // 2 MB
    float* ei_t = (float*)(ws + ((size_t)6 << 20));                   // 128 KB
    float* ej_t = ei_t + (size_t)B * H * N;                           // 128 KB

    gat_prep<<<512 + B * N / 32, 256, 0, stream>>>(h, W, a, adj, bias,
                                                   hpF, mbB, ei_t, ej_t);
    gat_attn<<<B * H * (N / 64), 512, 0, stream>>>(hpF, ei_t, ej_t, mbB, out);
}

// Round 21
// 33.999 us; speedup vs baseline: 1.1131x; 1.0118x over previous
//
#include <hip/hip_runtime.h>

constexpr int B = 8, N = 1024, FIN = 128, FOUT = 64, H = 4;
constexpr float LOG2E = 1.44269504f;

typedef __attribute__((ext_vector_type(8))) short short8;
typedef __attribute__((ext_vector_type(4))) short short4v;
typedef __attribute__((ext_vector_type(4))) float f32x4;

// f32 -> bf16 round-to-nearest-even (prep-kernel use only)
static __device__ inline unsigned short f2bf(float x) {
    union { float f; unsigned u; } v; v.f = x;
    unsigned r = v.u + 0x7fff + ((v.u >> 16) & 1);
    return (unsigned short)(r >> 16);
}

// ---------------------------------------------------------------------------
// Fused prep kernel — R20-verified VERBATIM.
// Blocks 0..511: mbB via coalesced LDS transpose. Blocks 512..767: h_prime
// MFMA GEMM + ei/ej.
// ---------------------------------------------------------------------------
__global__ __launch_bounds__(256) void gat_prep(
    const float* __restrict__ h,      // (B,N,FIN)
    const float* __restrict__ W,      // (H,FIN,FOUT)
    const float* __restrict__ a,      // (H,2*FOUT,1)
    const int*   __restrict__ adj,    // (N,N)
    const float* __restrict__ bias,   // (N,N)
    unsigned short* __restrict__ hpF, // fragment-order bf16 (4 MB)
    unsigned short* __restrict__ mbB, // fragment-order bf16 (2 MB)
    float* __restrict__ ei_t,         // (B,H,N) *LOG2E
    float* __restrict__ ej_t)         // (B,H,N) *LOG2E
{
    __shared__ float h_lds[32][132];
    const int t = threadIdx.x;

    if (blockIdx.x < 512) {           // ---- mb part: coalesced + LDS transpose ----
        unsigned short* mlds = reinterpret_cast<unsigned short*>(h_lds); // 4KB reuse
        const int bx = blockIdx.x;
        const int ti = bx >> 3;            // 16-row i-tile
        const int j0 = (bx & 7) * 128;     // 128-j slab

        const int r = t >> 4;
        const int g = t & 15;
        const size_t src = (size_t)(ti * 16 + r) * N + j0 + g * 8;
        const int4*   ap = reinterpret_cast<const int4*>(adj + src);
        const float4* bp = reinterpret_cast<const float4*>(bias + src);
        int4   a0 = ap[0], a1 = ap[1];
        float4 b0 = bp[0], b1 = bp[1];
        unsigned short q0 = f2bf(a0.x ? LOG2E * b0.x : -1e35f);
        unsigned short q1 = f2bf(a0.y ? LOG2E * b0.y : -1e35f);
        unsigned short q2 = f2bf(a0.z ? LOG2E * b0.z : -1e35f);
        unsigned short q3 = f2bf(a0.w ? LOG2E * b0.w : -1e35f);
        unsigned short q4 = f2bf(a1.x ? LOG2E * b1.x : -1e35f);
        unsigned short q5 = f2bf(a1.y ? LOG2E * b1.y : -1e35f);
        unsigned short q6 = f2bf(a1.z ? LOG2E * b1.z : -1e35f);
        unsigned short q7 = f2bf(a1.w ? LOG2E * b1.w : -1e35f);
        int4 ov;
        ov.x = (int)((unsigned)q0 | ((unsigned)q1 << 16));
        ov.y = (int)((unsigned)q2 | ((unsigned)q3 << 16));
        ov.z = (int)((unsigned)q4 | ((unsigned)q5 << 16));
        ov.w = (int)((unsigned)q6 | ((unsigned)q7 << 16));
        *reinterpret_cast<int4*>(&mlds[r * 128 + ((g ^ (r & 7)) * 8)]) = ov;
        __syncthreads();

        const int w    = t >> 6;
        const int lane = t & 63;
        const int li   = lane & 15;
        const int kg   = lane >> 4;
        const int gr   = w * 4 + kg;
        int4 ov2 = *reinterpret_cast<const int4*>(
            &mlds[li * 128 + ((gr ^ (li & 7)) * 8)]);
        const int jc = (bx & 7) * 4 + w;
        *reinterpret_cast<int4*>(mbB + (((size_t)ti * 32 + jc) * 64 + lane) * 8) = ov2;
        return;
    }

    // ---- h_prime part: MFMA, 32 rows per block, wave = head ----
    const int blk = blockIdx.x - 512;        // 0..255
    const int b   = blk >> 5;                // / (N/32)
    const int n0  = (blk & 31) * 32;

    {   // stage 32 rows x 128 f32 (16.9KB): 1024 float4, 4 per thread
        const float* src = h + ((size_t)b * N + n0) * FIN;
        for (int v = t; v < 1024; v += 256) {
            float4 x = reinterpret_cast<const float4*>(src)[v];
            int fl = v * 4;
            *reinterpret_cast<float4*>(&h_lds[fl >> 7][fl & 127]) = x;
        }
    }

    const int hd   = t >> 6;
    const int lane = t & 63;
    const int li   = lane & 15;
    const int kg   = lane >> 4;

    short8 wf[4][4];
    {
        const float* Wp = W + (size_t)hd * FIN * FOUT;
        #pragma unroll
        for (int ks = 0; ks < 4; ++ks)
            #pragma unroll
            for (int ft = 0; ft < 4; ++ft) {
                const float* wb = Wp + (size_t)(ks * 32 + 8 * kg) * FOUT + 16 * ft + li;
                int4 pk_;
                float u0 = wb[0],       u1 = wb[64],      u2 = wb[128], u3 = wb[192];
                float u4 = wb[256],     u5 = wb[320],     u6 = wb[384], u7 = wb[448];
                asm("v_cvt_pk_bf16_f32 %0, %1, %2" : "=v"(pk_.x) : "v"(u0), "v"(u1));
                asm("v_cvt_pk_bf16_f32 %0, %1, %2" : "=v"(pk_.y) : "v"(u2), "v"(u3));
                asm("v_cvt_pk_bf16_f32 %0, %1, %2" : "=v"(pk_.z) : "v"(u4), "v"(u5));
                asm("v_cvt_pk_bf16_f32 %0, %1, %2" : "=v"(pk_.w) : "v"(u6), "v"(u7));
                wf[ks][ft] = *reinterpret_cast<short8*>(&pk_);
            }
    }
    __syncthreads();                          // h_lds ready

    f32x4 c[4][2];
    #pragma unroll
    for (int ft = 0; ft < 4; ++ft)
        #pragma unroll
        for (int rt = 0; rt < 2; ++rt) c[ft][rt] = f32x4{0.f, 0.f, 0.f, 0.f};

    #pragma unroll
    for (int rt = 0; rt < 2; ++rt) {
        #pragma unroll
        for (int ks = 0; ks < 4; ++ks) {
            const float* hp8 = &h_lds[16 * rt + li][ks * 32 + 8 * kg];
            float4 x0 = *reinterpret_cast<const float4*>(hp8);
            float4 x1 = *reinterpret_cast<const float4*>(hp8 + 4);
            int4 pk_;
            asm("v_cvt_pk_bf16_f32 %0, %1, %2" : "=v"(pk_.x) : "v"(x0.x), "v"(x0.y));
            asm("v_cvt_pk_bf16_f32 %0, %1, %2" : "=v"(pk_.y) : "v"(x0.z), "v"(x0.w));
            asm("v_cvt_pk_bf16_f32 %0, %1, %2" : "=v"(pk_.z) : "v"(x1.x), "v"(x1.y));
            asm("v_cvt_pk_bf16_f32 %0, %1, %2" : "=v"(pk_.w) : "v"(x1.z), "v"(x1.w));
            short8 af = *reinterpret_cast<short8*>(&pk_);
            c[0][rt] = __builtin_amdgcn_mfma_f32_16x16x32_bf16(af, wf[ks][0], c[0][rt], 0, 0, 0);
            c[1][rt] = __builtin_amdgcn_mfma_f32_16x16x32_bf16(af, wf[ks][1], c[1][rt], 0, 0, 0);
            c[2][rt] = __builtin_amdgcn_mfma_f32_16x16x32_bf16(af, wf[ks][2], c[2][rt], 0, 0, 0);
            c[3][rt] = __builtin_amdgcn_mfma_f32_16x16x32_bf16(af, wf[ks][3], c[3][rt], 0, 0, 0);
        }
    }

    const int bh = b * H + hd;
    const int jc = n0 >> 5;
    #pragma unroll
    for (int ft = 0; ft < 4; ++ft)
        #pragma unroll
        for (int rt = 0; rt < 2; ++rt) {
            short4v v4;
            v4[0] = (short)f2bf(c[ft][rt][0]);
            v4[1] = (short)f2bf(c[ft][rt][1]);
            v4[2] = (short)f2bf(c[ft][rt][2]);
            v4[3] = (short)f2bf(c[ft][rt][3]);
            const int lanep = li + 16 * (2 * rt + (kg >> 1));
            *reinterpret_cast<short4v*>(
                hpF + ((((size_t)bh * 32 + jc) * 4 + ft) * 64 + lanep) * 8 + 4 * (kg & 1)) = v4;
        }

    float a1v[4], a2v[4];
    #pragma unroll
    for (int ft = 0; ft < 4; ++ft) {
        a1v[ft] = a[(size_t)hd * 2 * FOUT + 16 * ft + li];
        a2v[ft] = a[(size_t)hd * 2 * FOUT + FOUT + 16 * ft + li];
    }
    #pragma unroll
    for (int rt = 0; rt < 2; ++rt)
        #pragma unroll
        for (int r = 0; r < 4; ++r) {
            float e1 = c[0][rt][r] * a1v[0] + c[1][rt][r] * a1v[1]
                     + c[2][rt][r] * a1v[2] + c[3][rt][r] * a1v[3];
            float e2 = c[0][rt][r] * a2v[0] + c[1][rt][r] * a2v[1]
                     + c[2][rt][r] * a2v[2] + c[3][rt][r] * a2v[3];
            #pragma unroll
            for (int m = 1; m < 16; m <<= 1) {
                e1 += __shfl_xor(e1, m, 64);
                e2 += __shfl_xor(e2, m, 64);
            }
            if (li == 0) {
                int rr = n0 + 16 * rt + 4 * kg + r;
                ei_t[(size_t)bh * N + rr] = LOG2E * e1;
                ej_t[(size_t)bh * N + rr] = LOG2E * e2;
            }
        }
}

// ---------------------------------------------------------------------------
// Kernel B: fused scores+softmax+PV. NEW wave mapping (this round's single
// change): 8 waves = 2 i-supers (32 rows each) x 4 j-quarters (8 chunks each).
// Each staged V-frag is read by 2 waves instead of 4 (LDS read amplification
// halved; each DSREAD feeds 8 useful MFMAs). Wave (isup,jq) stages f-tiles
// {2isup, 2isup+1}. Ledger/phase: issue {STAGE x2, mqA,mqB,ejA,ejB}=6;
// vmcnt(4) retires the 2 STAGEs. 9 loop barriers (was 17). Combine: single
// round, 3 slots (jq 1..3) in 60KB red aliased over the dead stage region.
// All fragment layouts / score math identical to R17-R20 verified versions.
// ---------------------------------------------------------------------------
__global__ __launch_bounds__(512) void gat_attn(
    const unsigned short* __restrict__ hpF, // fragment-order bf16
    const float* __restrict__ ei_t,         // (B,H,N) *LOG2E
    const float* __restrict__ ej_t,         // (B,H,N) *LOG2E
    const unsigned short* __restrict__ mbB, // fragment-order bf16 masked bias
    float* __restrict__ out)                // (B,N,H*FOUT)
{
    __shared__ __align__(16) char smem[61440];  // stage 32KB (front); red[3][2][10][64] f32x4 aliased
    typedef unsigned short hstage_t[4][4][512]; // [jq][ft][lane*8+e]
    hstage_t* hstage = reinterpret_cast<hstage_t*>(smem);  // [2 bufs]

    const int raw  = blockIdx.x;            // 512
    const int xcd  = raw & 7;
    const int k_   = raw >> 3;
    const int bh   = ((xcd >> 1) << 3) | (k_ >> 3);          // 8 bh per XCD
    const int it0  = (((xcd & 1) << 3) | (k_ & 7)) * 4;      // 4 i-tiles/block
    const int t    = threadIdx.x;
    const int w8   = t >> 6;
    const int isup = w8 & 1;                // i-super: i-tiles {it0+2isup, +1}
    const int jq   = w8 >> 1;               // j-quarter: chunks jq*8..jq*8+7
    const int lane = t & 63;
    const int li   = lane & 15;
    const int kg   = lane >> 4;
    const int tiA  = it0 + 2 * isup;
    const int tiB  = tiA + 1;
    const int jqb  = jq * 8;

    const float ei0a = ei_t[(size_t)bh * N + tiA * 16 + li];
    const float ei0b = ei_t[(size_t)bh * N + tiB * 16 + li];
    const float* ejrow = ej_t + (size_t)bh * N;
    const unsigned short* mrowA = mbB + ((size_t)tiA * 32 * 64 + lane) * 8;
    const unsigned short* mrowB = mbB + ((size_t)tiB * 32 * 64 + lane) * 8;
    const size_t hbase = (size_t)bh * 65536;                 // u16/slab

    f32x4 cA0 = {0,0,0,0}, cA1 = {0,0,0,0}, cA2 = {0,0,0,0}, cA3 = {0,0,0,0};
    f32x4 cB0 = {0,0,0,0}, cB1 = {0,0,0,0}, cB2 = {0,0,0,0}, cB3 = {0,0,0,0};
    f32x4 c4a = {0,0,0,0}, c4b = {0,0,0,0};
    const short obf = (short)0x3F80;                         // bf16 1.0
    const short8 ones = {obf,obf,obf,obf,obf,obf,obf,obf};

    #define VMCNT4() asm volatile("s_waitcnt vmcnt(4)" ::: "memory")
    #define BARRIER() { __builtin_amdgcn_s_barrier(); asm volatile("" ::: "memory"); }

    // stage f-tiles {2isup, 2isup+1} of chunk JCG into hstage[BUF][jq]
    #define STAGE(BUF, JCG) {                                                   \
        const unsigned short* g0_ = hpF + hbase + (size_t)(JCG) * 2048          \
                                  + (size_t)(2 * isup) * 512 + (size_t)lane * 8;\
        __builtin_amdgcn_global_load_lds(                                       \
            (const __attribute__((address_space(1))) void*)g0_,                 \
            (__attribute__((address_space(3))) void*)&hstage[BUF][jq][2 * isup][0], \
            16, 0, 0);                                                          \
        __builtin_amdgcn_global_load_lds(                                       \
            (const __attribute__((address_space(1))) void*)(g0_ + 512),         \
            (__attribute__((address_space(3))) void*)&hstage[BUF][jq][2 * isup + 1][0], \
            16, 0, 0); }

    #define REGS(JCG) {                                                         \
        mqA  = *reinterpret_cast<const int4*>(mrowA + (size_t)(JCG) * 512);     \
        mqB  = *reinterpret_cast<const int4*>(mrowB + (size_t)(JCG) * 512);     \
        ejA  = *reinterpret_cast<const float4*>(ejrow + (JCG) * 32 + 8 * kg);   \
        ejB  = *reinterpret_cast<const float4*>(ejrow + (JCG) * 32 + 8 * kg + 4); }

    #define DSREAD(BUF) {                                                       \
        V0 = *reinterpret_cast<const short8*>(&hstage[BUF][jq][0][lane * 8]);   \
        V1 = *reinterpret_cast<const short8*>(&hstage[BUF][jq][1][lane * 8]);   \
        V2 = *reinterpret_cast<const short8*>(&hstage[BUF][jq][2][lane * 8]);   \
        V3 = *reinterpret_cast<const short8*>(&hstage[BUF][jq][3][lane * 8]); }

    #define SCORE2(PL, PH, EI, EJL, EJH, QW) {                                  \
        float bl_ = __uint_as_float(((unsigned)(QW)) << 16);                    \
        float bh_ = __uint_as_float(((unsigned)(QW)) & 0xffff0000u);            \
        float el_ = (EI) + (EJL); el_ = fmaxf(el_, 0.2f * el_) + bl_;           \
        float eh_ = (EI) + (EJH); eh_ = fmaxf(eh_, 0.2f * eh_) + bh_;           \
        asm("v_exp_f32 %0, %1" : "=v"(PL) : "v"(el_));                          \
        asm("v_exp_f32 %0, %1" : "=v"(PH) : "v"(eh_)); }

    #define AFRAG(DST, EI, MQ) {                                                \
        float p0,p1,p2,p3,p4,p5,p6,p7;                                          \
        SCORE2(p0, p1, EI, ejA.x, ejA.y, MQ.x)                                  \
        SCORE2(p2, p3, EI, ejA.z, ejA.w, MQ.y)                                  \
        SCORE2(p4, p5, EI, ejB.x, ejB.y, MQ.z)                                  \
        SCORE2(p6, p7, EI, ejB.z, ejB.w, MQ.w)                                  \
        int4 pk_;                                                               \
        asm("v_cvt_pk_bf16_f32 %0, %1, %2" : "=v"(pk_.x) : "v"(p0), "v"(p1));   \
        asm("v_cvt_pk_bf16_f32 %0, %1, %2" : "=v"(pk_.y) : "v"(p2), "v"(p3));   \
        asm("v_cvt_pk_bf16_f32 %0, %1, %2" : "=v"(pk_.z) : "v"(p4), "v"(p5));   \
        asm("v_cvt_pk_bf16_f32 %0, %1, %2" : "=v"(pk_.w) : "v"(p6), "v"(p7));   \
        DST = *reinterpret_cast<short8*>(&pk_); }

    #define COMPS() {                                                           \
        short8 aA_, aB_;                                                        \
        AFRAG(aA_, ei0a, mqA)                                                   \
        cA0 = __builtin_amdgcn_mfma_f32_16x16x32_bf16(aA_, V0, cA0, 0, 0, 0);   \
        cA1 = __builtin_amdgcn_mfma_f32_16x16x32_bf16(aA_, V1, cA1, 0, 0, 0);   \
        cA2 = __builtin_amdgcn_mfma_f32_16x16x32_bf16(aA_, V2, cA2, 0, 0, 0);   \
        cA3 = __builtin_amdgcn_mfma_f32_16x16x32_bf16(aA_, V3, cA3, 0, 0, 0);   \
        c4a = __builtin_amdgcn_mfma_f32_16x16x32_bf16(aA_, ones, c4a, 0, 0, 0); \
        AFRAG(aB_, ei0b, mqB)                                                   \
        cB0 = __builtin_amdgcn_mfma_f32_16x16x32_bf16(aB_, V0, cB0, 0, 0, 0);   \
        cB1 = __builtin_amdgcn_mfma_f32_16x16x32_bf16(aB_, V1, cB1, 0, 0, 0);   \
        cB2 = __builtin_amdgcn_mfma_f32_16x16x32_bf16(aB_, V2, cB2, 0, 0, 0);   \
        cB3 = __builtin_amdgcn_mfma_f32_16x16x32_bf16(aB_, V3, cB3, 0, 0, 0);   \
        c4b = __builtin_amdgcn_mfma_f32_16x16x32_bf16(aB_, ones, c4b, 0, 0, 0); }

    short8 V0, V1, V2, V3;
    int4 mqA, mqB;
    float4 ejA, ejB;

    // prologue: stage + regs for chunk jqb
    STAGE(0, jqb)
    REGS(jqb)
    VMCNT4();                                // the 2 STAGEs retired
    BARRIER();

    #pragma unroll 1
    for (int k = 0; k < 8; ++k) {
        const int nxt = (k + 1 < 8) ? jqb + k + 1 : jqb + 7;   // clamped
        STAGE((k + 1) & 1, nxt)
        DSREAD(k & 1)
        COMPS()
        REGS(nxt)
        VMCNT4();                            // retires this phase's 2 STAGEs
        BARRIER();
    }
    #undef VMCNT4
    #undef BARRIER
    #undef STAGE
    #undef REGS
    #undef DSREAD
    #undef SCORE2
    #undef AFRAG
    #undef COMPS

    // stage region dead: alias the combine buffer. red[slot 0..2][isup][regset][lane]
    f32x4 (*red)[2][10][64] = reinterpret_cast<f32x4 (*)[2][10][64]>(smem);

    __syncthreads();
    if (jq != 0) {
        f32x4 (*slot)[64] = red[jq - 1][isup];
        slot[0][lane] = cA0; slot[1][lane] = cA1;
        slot[2][lane] = cA2; slot[3][lane] = cA3;
        slot[4][lane] = cB0; slot[5][lane] = cB1;
        slot[6][lane] = cB2; slot[7][lane] = cB3;
        slot[8][lane] = c4a; slot[9][lane] = c4b;
    }
    __syncthreads();
    if (jq != 0) return;

    #pragma unroll
    for (int s = 0; s < 3; ++s) {
        f32x4 (*slot)[64] = red[s][isup];
        cA0 += slot[0][lane]; cA1 += slot[1][lane];
        cA2 += slot[2][lane]; cA3 += slot[3][lane];
        cB0 += slot[4][lane]; cB1 += slot[5][lane];
        cB2 += slot[6][lane]; cB3 += slot[7][lane];
        c4a += slot[8][lane]; c4b += slot[9][lane];
    }

    // write both i-tiles. C layout col=li, row=4*kg+r; c4x[r] = row sum.
    const int b  = bh >> 2;
    const int hd = bh & 3;
    #pragma unroll
    for (int r = 0; r < 4; ++r) {
        int orow = tiA * 16 + 4 * kg + r;
        float inv = 1.0f / c4a[r];
        float* ob = out + (((size_t)b * N + orow) * H + hd) * 64 + li;
        ob[0]  = cA0[r] * inv;
        ob[16] = cA1[r] * inv;
        ob[32] = cA2[r] * inv;
        ob[48] = cA3[r] * inv;
    }
    #pragma unroll
    for (int r = 0; r < 4; ++r) {
        int orow = tiB * 16 + 4 * kg + r;
        float inv = 1.0f / c4b[r];
        float* ob = out + (((size_t)b * N + orow) * H + hd) * 64 + li;
        ob[0]  = cB0[r] * inv;
        ob[16] = cB1[r] * inv;
        ob[32] = cB2[r] * inv;
        ob[48] = cB3[r] * inv;
    }
}

extern "C" void kernel_launch(void* const* d_in, const int* in_sizes, int n_in,
                              void* d_out, int out_size, void* d_ws, size_t ws_size,
                              hipStream_t stream) {
    const float* h    = (const float*)d_in[0];
    const int*   adj  = (const int*)  d_in[1];
    const float* bias = (const float*)d_in[2];
    const float* W    = (const float*)d_in[3];
    const float* a    = (const float*)d_in[4];
    float* out = (float*)d_out;

    char* ws = (char*)d_ws;
    unsigned short* hpF = (unsigned short*)ws;                        // 4 MB
    unsigned short* mbB = (unsigned short*)(ws + ((size_t)4 << 20));  // 2 MB
    float* ei_t = (float*)(ws + ((size_t)6 << 20));                   // 128 KB
    float* ej_t = ei_t + (size_t)B * H * N;                           // 128 KB

    gat_prep<<<512 + B * N / 32, 256, 0, stream>>>(h, W, a, adj, bias,
                                                   hpF, mbB, ei_t, ej_t);
    gat_attn<<<B * H * (N / 64), 512, 0, stream>>>(hpF, ei_t, ej_t, mbB, out);
}